// Round 8
// baseline (172.229 us; speedup 1.0000x reference)
//
#include <hip/hip_runtime.h>
#include <stdint.h>

#define BROWS 16384
#define DDIM  512
#define EEXP  16
#define HDIM  256
#define LDIM  64
#define BM    64

typedef __bf16  bf16x8  __attribute__((ext_vector_type(8)));
typedef float   floatx4 __attribute__((ext_vector_type(4)));
typedef ushort  ushort8 __attribute__((ext_vector_type(8)));
typedef unsigned int u32;

__device__ __forceinline__ ushort f2bf(float f) {
    uint32_t u = __builtin_bit_cast(uint32_t, f);
    u += 0x7fffu + ((u >> 16) & 1u);   // RNE
    return (ushort)(u >> 16);
}

// tanh(x) = 1 - 2/(exp2(2x*log2e)+1); saturates correctly, rel err ~1e-6.
__device__ __forceinline__ float fast_tanh(float x) {
    float e = __builtin_amdgcn_exp2f(x * 2.8853900817779268f);
    return 1.0f - 2.0f * __builtin_amdgcn_rcpf(e + 1.0f);
}

__device__ __forceinline__ void gl_lds16(const void* g, void* l) {
    __builtin_amdgcn_global_load_lds(
        (const __attribute__((address_space(1))) u32*)g,
        (__attribute__((address_space(3))) u32*)l, 16, 0, 0);
}

// ---------------------------------------------------------------------------
// MERGED kernel (unchanged from R7). Blocks 0..511: gating, double-buffered
// chunks + fused x->bf16 swizzled cvt + atomic rowlist + coalesced zero-fill.
// Blocks 512..1087: W1/W2 transpose as 64x64 float4 tiles.
// ---------------------------------------------------------------------------
__global__ __launch_bounds__(256) void gate_aux_kernel(
    const float* __restrict__ x,      // [B][D]
    const float* __restrict__ noise,  // [B][E]
    const float* __restrict__ wg,     // [D][E]
    const float* __restrict__ wn,     // [D][E]
    const float* __restrict__ W1,     // [E][D][H]
    const float* __restrict__ W2,     // [E][H][L]
    float* __restrict__ gates,        // [B][E]
    ushort* __restrict__ xbf,         // [B][D] bf16 swizzled
    ushort* __restrict__ W1T,         // [E][H][D] bf16 swizzled
    ushort* __restrict__ W2T,         // [E][L][H] bf16 linear
    u32* __restrict__ cnt,            // [E] (pre-zeroed)
    u32* __restrict__ rowlist,        // [E][B] unsorted-compact
    float* __restrict__ out)          // [B][E][L]
{
    __shared__ __align__(16) float smbig[16896];   // 66 KB
    __shared__ u32 lcnt[16];
    __shared__ u32 lbase[16];
    __shared__ ushort lrows[16 * 32];
    __shared__ u32 izn;
    __shared__ ushort izlist[512];

    if (blockIdx.x >= 512) {
        // ---- transpose path: 64x64 tiles ----
        float (*tile)[68] = reinterpret_cast<float(*)[68]>(smbig);
        int b = blockIdx.x - 512;
        const float* src; ushort* dst; int R, C, c0, r0, swz, ei;
        if (b < 512) {                     // W1: [512][256] -> [256][512] swz
            ei = b >> 5; int rem = b & 31;
            r0 = (rem >> 2) * 64; c0 = (rem & 3) * 64;
            R = DDIM; C = HDIM; swz = 1;
            src = W1; dst = W1T;
        } else {                           // W2: [256][64] -> [64][256]
            b -= 512;
            ei = b >> 2; int rem = b & 3;
            r0 = rem * 64; c0 = 0;
            R = HDIM; C = LDIM; swz = 0;
            src = W2; dst = W2T;
        }
        const int tr  = threadIdx.x >> 2;        // 0..63 source row
        const int tc4 = threadIdx.x & 3;         // 4 col-slots of 16

        const float* s = src + (size_t)ei * R * C + (size_t)(r0 + tr) * C + c0 + tc4 * 16;
        #pragma unroll
        for (int i = 0; i < 4; ++i) {
            float4 v = *reinterpret_cast<const float4*>(s + i * 4);
            *reinterpret_cast<float4*>(&tile[tr][tc4 * 16 + i * 4]) = v;
        }
        __syncthreads();

        ushort* d = dst + (size_t)ei * R * C;
        const int hh = c0 + tr;                  // output row (C-dim)
        #pragma unroll
        for (int i = 0; i < 4; ++i) {
            int rrb  = tc4 * 16 + i * 4;         // tile row = source-row offset
            int colb = r0 + rrb;                 // output col (R-dim)
            int col2 = colb;
            if (swz) {
                int g = (colb >> 3) & 7;
                col2 = (colb & ~63) | ((g ^ (hh & 7)) << 3) | (colb & 7);
            }
            ushort4 o;
            o.x = f2bf(tile[rrb + 0][tr]);
            o.y = f2bf(tile[rrb + 1][tr]);
            o.z = f2bf(tile[rrb + 2][tr]);
            o.w = f2bf(tile[rrb + 3][tr]);
            *reinterpret_cast<ushort4*>(&d[(size_t)hh * R + col2]) = o;
        }
        return;
    }

    // ---- gating path ----
    float* xs  = smbig;                  // [2][32*132]
    float* wtg = smbig + 2 * 32 * 132;   // [2][16*132]
    float* wtn = wtg   + 2 * 16 * 132;   // [2][16*132]

    const int t    = threadIdx.x;
    const int blk  = blockIdx.x;
    const int row0 = blk * 32;
    const int og   = t & 15, rg = t >> 4;
    const int sr   = t >> 3, sc = (t & 7) * 16;   // x-stage row/col
    const int sd   = t >> 1, se = (t & 1) * 8;    // w-stage d/e0

    if (t < 16) lcnt[t] = 0;
    if (t == 0) izn = 0;

    float4 xf0, xf1, xf2, xf3, wg0, wg1, wn0, wn1;
    const float* srcx0 = &x[(size_t)(row0 + sr) * DDIM + sc];

    // issue chunk-0 loads
    {
        const float4* p = reinterpret_cast<const float4*>(srcx0);
        xf0 = p[0]; xf1 = p[1]; xf2 = p[2]; xf3 = p[3];
        const float4* pg = reinterpret_cast<const float4*>(&wg[(size_t)sd * EEXP + se]);
        const float4* pn = reinterpret_cast<const float4*>(&wn[(size_t)sd * EEXP + se]);
        wg0 = pg[0]; wg1 = pg[1]; wn0 = pn[0]; wn1 = pn[1];
    }

    floatx4 accg4[2] = {}, accn4[2] = {};

    for (int ch = 0; ch < 4; ++ch) {
        const int k0  = ch * 128;
        const int buf = ch & 1;
        float* xsb = xs  + buf * (32 * 132);
        float* wgl = wtg + buf * (16 * 132);
        float* wnl = wtn + buf * (16 * 132);

        {   // LDS writes + xbf writeback (from regs loaded last iteration)
            float* dstx = &xsb[sr * 132 + sc];
            reinterpret_cast<float4*>(dstx)[0] = xf0;
            reinterpret_cast<float4*>(dstx)[1] = xf1;
            reinterpret_cast<float4*>(dstx)[2] = xf2;
            reinterpret_cast<float4*>(dstx)[3] = xf3;

            const int row = row0 + sr;
            const int sw  = sr & 7;
            #pragma unroll
            for (int i = 0; i < 2; ++i) {
                int cb = k0 + sc + i * 8;
                int kb = cb >> 6;
                int g  = (cb >> 3) & 7;
                int gp = g ^ sw;
                float4 a = (i == 0) ? xf0 : xf2;
                float4 b = (i == 0) ? xf1 : xf3;
                ushort8 t8;
                t8[0]=f2bf(a.x); t8[1]=f2bf(a.y); t8[2]=f2bf(a.z); t8[3]=f2bf(a.w);
                t8[4]=f2bf(b.x); t8[5]=f2bf(b.y); t8[6]=f2bf(b.z); t8[7]=f2bf(b.w);
                *reinterpret_cast<ushort8*>(&xbf[(size_t)row * DDIM + kb * 64 + gp * 8]) = t8;
            }

            wgl[(se+0)*132+sd]=wg0.x; wgl[(se+1)*132+sd]=wg0.y; wgl[(se+2)*132+sd]=wg0.z; wgl[(se+3)*132+sd]=wg0.w;
            wgl[(se+4)*132+sd]=wg1.x; wgl[(se+5)*132+sd]=wg1.y; wgl[(se+6)*132+sd]=wg1.z; wgl[(se+7)*132+sd]=wg1.w;
            wnl[(se+0)*132+sd]=wn0.x; wnl[(se+1)*132+sd]=wn0.y; wnl[(se+2)*132+sd]=wn0.z; wnl[(se+3)*132+sd]=wn0.w;
            wnl[(se+4)*132+sd]=wn1.x; wnl[(se+5)*132+sd]=wn1.y; wnl[(se+6)*132+sd]=wn1.z; wnl[(se+7)*132+sd]=wn1.w;
        }

        if (ch < 3) {   // issue next chunk's loads; land during barrier+compute
            const int k1 = k0 + 128;
            const float4* p = reinterpret_cast<const float4*>(srcx0 + k1);
            xf0 = p[0]; xf1 = p[1]; xf2 = p[2]; xf3 = p[3];
            const float4* pg = reinterpret_cast<const float4*>(&wg[(size_t)(k1 + sd) * EEXP + se]);
            const float4* pn = reinterpret_cast<const float4*>(&wn[(size_t)(k1 + sd) * EEXP + se]);
            wg0 = pg[0]; wg1 = pg[1]; wn0 = pn[0]; wn1 = pn[1];
        }

        __syncthreads();   // single barrier/chunk (writes go to buf^1 next)

        #pragma unroll 8
        for (int d4 = 0; d4 < 32; ++d4) {
            floatx4 wgv = *reinterpret_cast<const floatx4*>(&wgl[og * 132 + d4 * 4]);
            floatx4 wnv = *reinterpret_cast<const floatx4*>(&wnl[og * 132 + d4 * 4]);
            #pragma unroll
            for (int rr = 0; rr < 2; ++rr) {
                floatx4 xv = *reinterpret_cast<const floatx4*>(&xsb[(rg * 2 + rr) * 132 + d4 * 4]);
                accg4[rr] += xv * wgv;
                accn4[rr] += xv * wnv;
            }
        }
    }

    #pragma unroll
    for (int rr = 0; rr < 2; ++rr) {
        const int row = row0 + rg * 2 + rr;
        float accg = accg4[rr][0] + accg4[rr][1] + accg4[rr][2] + accg4[rr][3];
        float accn = accn4[rr][0] + accn4[rr][1] + accn4[rr][2] + accn4[rr][3];

        // keep libcall-precision softplus: gate threshold flips are the risk
        float sp = fmaxf(accn, 0.f) + log1pf(expf(-fabsf(accn)));
        float stddev = sp + 0.01f;
        float nz = noise[(size_t)row * EEXP + og];
        float z = accg + nz * stddev;

        float m = z;
        #pragma unroll
        for (int mask = 8; mask >= 1; mask >>= 1)
            m = fmaxf(m, __shfl_xor(m, mask, 16));
        float ez = expf(z - m);
        float s = ez;
        #pragma unroll
        for (int mask = 8; mask >= 1; mask >>= 1)
            s += __shfl_xor(s, mask, 16);
        float logit = ez / s;

        float lsum = logit;
        #pragma unroll
        for (int mask = 8; mask >= 1; mask >>= 1)
            lsum += __shfl_xor(lsum, mask, 16);
        float mean = lsum * (1.0f / 16.0f) - 1e-8f;

        float gate = (logit >= mean) ? logit : 0.0f;
        float denom = gate;
        #pragma unroll
        for (int mask = 8; mask >= 1; mask >>= 1)
            denom += __shfl_xor(denom, mask, 16);

        gates[(size_t)row * EEXP + og] = gate / denom;

        if (gate > 0.0f) {
            u32 p = atomicAdd(&lcnt[og], 1u);
            lrows[og * 32 + p] = (ushort)(rg * 2 + rr);
        } else {
            u32 p = atomicAdd(&izn, 1u);
            izlist[p] = (ushort)((rg * 2 + rr) * 16 + og);
        }
    }

    __syncthreads();
    if (t < 16) lbase[t] = atomicAdd(&cnt[t], lcnt[t]);

    // Coalesced zero-fill: 16 consecutive threads per inactive slot write one
    // contiguous 256-B segment (16 x float4).
    {
        const u32 ni = izn;
        const int grp = t >> 4, l16 = t & 15;
        float4* o4 = reinterpret_cast<float4*>(out);
        const float4 zf = {0.f, 0.f, 0.f, 0.f};
        for (u32 i = grp; i < ni; i += 16) {
            int slot = izlist[i];
            int rl = slot >> 4, e = slot & 15;
            o4[(size_t)(row0 + rl) * 256 + e * 16 + l16] = zf;
        }
    }

    __syncthreads();
    for (int i = t; i < 16 * 32; i += 256) {
        int e = i >> 5, j = i & 31;
        if ((u32)j < lcnt[e])
            rowlist[(size_t)e * BROWS + lbase[e] + j] = row0 + lrows[e * 32 + j];
    }
}

// ---------------------------------------------------------------------------
// Sparse expert MLP, BM=64, 40 KB LDS -> 4 blocks/CU. IDENTICAL to the
// proven-best structure except K-PHASE DESYNC: each block starts its K-loop
// at a rotated step (phase = (bx>>8)&7). Co-resident blocks on a CU
// (bx, bx+256, bx+512, bx+768) get consecutive phases -> their 40 KB staging
// bursts interleave with neighbors' compute instead of coinciding, smoothing
// L2 demand (kernel moves 1.31 GB through L2 ~ 70% of ceiling, bursty).
// K-step accumulation is commutative -> bit-level FP reorder only.
// ---------------------------------------------------------------------------
__global__ __launch_bounds__(256, 4) void expert_kernel(
    const ushort* __restrict__ xbf,    // [B][D] bf16, swizzled
    const float*  __restrict__ gates,  // [B][E]
    const ushort* __restrict__ W1T,    // [E][H][D] bf16, swizzled
    const float*  __restrict__ b1,     // [E][H]
    const ushort* __restrict__ W2T,    // [E][L][H] bf16, linear
    const float*  __restrict__ b2,     // [E][L]
    const u32*    __restrict__ cnt,    // [E]
    const u32*    __restrict__ rowlist,// [E][B]
    float* __restrict__ out)           // [B][E][L]
{
    __shared__ __align__(16) ushort lds[20480];  // A [0,8K)B, B [8K,40K)B; h [0,32K)B

    const int bx = blockIdx.x;
    const int e  = bx & 15;
    const int t  = bx >> 4;

    const int count = (int)cnt[e];
    if (t * BM >= count) return;
    const int nrt = min(BM, count - t * BM);
    const u32* rl = rowlist + (size_t)e * BROWS + t * BM;

    const int tid  = threadIdx.x;
    const int lane = tid & 63;
    const int wave = tid >> 6;

    const int lr = lane & 15;
    const int q  = lane >> 4;
    const int kq = q * 8;
    const int rq = q * 4;
    const int la = lane >> 3, lb = lane & 7;  // staging lane split

    const char* xg = (const char*)xbf;
    const char* w1 = (const char*)W1T + (size_t)e * HDIM * 1024;

    // Per-lane gathered A-row bases + swizzle re-key terms
    size_t abase[2]; int sxr[2];
    #pragma unroll
    for (int p = 0; p < 2; ++p) {
        int r  = wave * 16 + p * 8 + la;
        int rc = min(r, nrt - 1);
        u32 ri = rl[rc];
        abase[p] = (size_t)ri * 1024;
        sxr[p]   = (la ^ (int)(ri & 7)) << 4;
    }

    const int phase = (bx >> 8) & 7;   // co-resident blocks -> distinct phases

    floatx4 acc[4][4] = {};

    for (int kk = 0; kk < 8; ++kk) {
        const int kb   = (kk + phase) & 7;
        const int koff = kb * 128;   // byte offset within 1024-B row
        #pragma unroll
        for (int p = 0; p < 2; ++p) {   // A tile: 8 KB (gathered rows)
            int c = wave * 2 + p;
            gl_lds16(xg + abase[p] + koff + ((lb << 4) ^ sxr[p]), &lds[c * 512]);
        }
        #pragma unroll
        for (int p = 0; p < 8; ++p) {   // B tile: 32 KB (sequential W1T rows)
            int c = wave * 8 + p;
            gl_lds16(w1 + (size_t)(c * 8 + la) * 1024 + koff + (lb << 4),
                     &lds[4096 + c * 512]);
        }
        __syncthreads();

        #pragma unroll
        for (int s = 0; s < 2; ++s) {
            const int g = s * 4 + q;
            bf16x8 af[4], bfr[4];
            #pragma unroll
            for (int i = 0; i < 4; ++i) {
                int r = i * 16 + lr;
                af[i] = *reinterpret_cast<const bf16x8*>(&lds[r * 64 + ((g ^ (r & 7)) << 3)]);
            }
            #pragma unroll
            for (int j = 0; j < 4; ++j) {
                int r = wave * 64 + j * 16 + lr;
                bfr[j] = *reinterpret_cast<const bf16x8*>(&lds[4096 + r * 64 + ((g ^ (r & 7)) << 3)]);
            }
            #pragma unroll
            for (int i = 0; i < 4; ++i)
                #pragma unroll
                for (int j = 0; j < 4; ++j)
                    acc[i][j] = __builtin_amdgcn_mfma_f32_16x16x32_bf16(
                        af[i], bfr[j], acc[i][j], 0, 0, 0);
        }
        __syncthreads();
    }

    // h = fast_tanh(acc + b1) -> bf16, swizzled [64][256] at lds[0..32K)
    float b1v[4];
    #pragma unroll
    for (int j = 0; j < 4; ++j)
        b1v[j] = b1[e * HDIM + wave * 64 + j * 16 + lr];

    #pragma unroll
    for (int i = 0; i < 4; ++i)
        #pragma unroll
        for (int j = 0; j < 4; ++j) {
            int c = wave * 64 + j * 16 + lr;
            int gg = c >> 3;
            #pragma unroll
            for (int rr = 0; rr < 4; ++rr) {
                int r = i * 16 + rq + rr;
                float v = fast_tanh(acc[i][j][rr] + b1v[j]);
                lds[r * 256 + (((gg & 24) | ((gg & 7) ^ (r & 7))) << 3) + (c & 7)] = f2bf(v);
            }
        }
    __syncthreads();

    // Phase B: y[64][64]; wave owns rows [wave*16,+16); W2 frags from global
    const ushort* w2 = W2T + (size_t)e * LDIM * HDIM;
    floatx4 acc2[4] = {};
    #pragma unroll
    for (int s = 0; s < 8; ++s) {
        int r = wave * 16 + lr;
        int g = s * 4 + q;
        bf16x8 af = *reinterpret_cast<const bf16x8*>(
            &lds[r * 256 + (((g & 24) | ((g & 7) ^ (r & 7))) << 3)]);
        #pragma unroll
        for (int j = 0; j < 4; ++j) {
            bf16x8 bfr = *reinterpret_cast<const bf16x8*>(
                &w2[(size_t)(j * 16 + lr) * HDIM + s * 32 + kq]);
            acc2[j] = __builtin_amdgcn_mfma_f32_16x16x32_bf16(af, bfr, acc2[j], 0, 0, 0);
        }
    }

    float b2v[4];
    #pragma unroll
    for (int j = 0; j < 4; ++j)
        b2v[j] = b2[e * LDIM + j * 16 + lr];

    #pragma unroll
    for (int rr = 0; rr < 4; ++rr) {
        int r  = wave * 16 + rq + rr;
        int rc = min(r, nrt - 1);
        u32 ri = rl[rc];
        float gsc = gates[(size_t)ri * EEXP + e];
        if (r < nrt) {
            #pragma unroll
            for (int j = 0; j < 4; ++j)
                out[(size_t)ri * (EEXP * LDIM) + e * LDIM + j * 16 + lr] =
                    (acc2[j][rr] + b2v[j]) * gsc;
        }
    }
}

// ---------------------------------------------------------------------------
extern "C" void kernel_launch(void* const* d_in, const int* in_sizes, int n_in,
                              void* d_out, int out_size, void* d_ws, size_t ws_size,
                              hipStream_t stream) {
    (void)in_sizes; (void)n_in; (void)out_size; (void)ws_size;
    const float* x     = (const float*)d_in[0];
    const float* noise = (const float*)d_in[1];
    const float* wg    = (const float*)d_in[2];
    const float* wn    = (const float*)d_in[3];
    const float* W1    = (const float*)d_in[4];
    const float* b1    = (const float*)d_in[5];
    const float* W2    = (const float*)d_in[6];
    const float* b2    = (const float*)d_in[7];
    float* out = (float*)d_out;

    char* ws = (char*)d_ws;
    float*  gates   = (float*)ws;                          // 1 MiB
    ushort* W1T     = (ushort*)(ws + (1 << 20));           // 4 MiB
    ushort* W2T     = (ushort*)(ws + (5 << 20));           // 0.5 MiB
    ushort* xbf     = (ushort*)(ws + (6 << 20));           // 16 MiB
    u32*    cnt     = (u32*)(ws + (22 << 20));             // 64 B
    u32*    rowlist = (u32*)(ws + (24 << 20));             // 1 MiB

    hipMemsetAsync(cnt, 0, EEXP * sizeof(u32), stream);
    gate_aux_kernel<<<512 + 576, 256, 0, stream>>>(
        x, noise, wg, wn, W1, W2, gates, xbf, W1T, W2T, cnt, rowlist, out);
    expert_kernel<<<(BROWS / BM) * EEXP, 256, 0, stream>>>(
        xbf, gates, W1T, b1, W2T, b2, cnt, rowlist, out);
}

// Round 9
// 170.039 us; speedup vs baseline: 1.0129x; 1.0129x over previous
//
#include <hip/hip_runtime.h>
#include <stdint.h>

#define BROWS 16384
#define DDIM  512
#define EEXP  16
#define HDIM  256
#define LDIM  64
#define BM    64

typedef __bf16  bf16x8  __attribute__((ext_vector_type(8)));
typedef float   floatx4 __attribute__((ext_vector_type(4)));
typedef ushort  ushort8 __attribute__((ext_vector_type(8)));
typedef unsigned int u32;

__device__ __forceinline__ ushort f2bf(float f) {
    uint32_t u = __builtin_bit_cast(uint32_t, f);
    u += 0x7fffu + ((u >> 16) & 1u);   // RNE
    return (ushort)(u >> 16);
}

// tanh(x) = 1 - 2/(exp2(2x*log2e)+1); saturates correctly, rel err ~1e-6.
__device__ __forceinline__ float fast_tanh(float x) {
    float e = __builtin_amdgcn_exp2f(x * 2.8853900817779268f);
    return 1.0f - 2.0f * __builtin_amdgcn_rcpf(e + 1.0f);
}

__device__ __forceinline__ void gl_lds16(const void* g, void* l) {
    __builtin_amdgcn_global_load_lds(
        (const __attribute__((address_space(1))) u32*)g,
        (__attribute__((address_space(3))) u32*)l, 16, 0, 0);
}

// ---------------------------------------------------------------------------
// MERGED kernel. Blocks 0..511: gating with async-staged double-buffered
// chunks (1 barrier/chunk) + fused x->bf16 swizzled cvt + atomic rowlist +
// coalesced zero-fill. Blocks 512..1087: W1/W2 transpose as 64x64 float4
// tiles with ushort4 swizzle-preserving stores.
// ---------------------------------------------------------------------------
__global__ __launch_bounds__(256) void gate_aux_kernel(
    const float* __restrict__ x,      // [B][D]
    const float* __restrict__ noise,  // [B][E]
    const float* __restrict__ wg,     // [D][E]
    const float* __restrict__ wn,     // [D][E]
    const float* __restrict__ W1,     // [E][D][H]
    const float* __restrict__ W2,     // [E][H][L]
    float* __restrict__ gates,        // [B][E]
    ushort* __restrict__ xbf,         // [B][D] bf16 swizzled
    ushort* __restrict__ W1T,         // [E][H][D] bf16 swizzled
    ushort* __restrict__ W2T,         // [E][L][H] bf16 linear
    u32* __restrict__ cnt,            // [E] (pre-zeroed)
    u32* __restrict__ rowlist,        // [E][B] unsorted-compact
    float* __restrict__ out)          // [B][E][L]
{
    __shared__ __align__(16) float smbig[16896];   // 66 KB
    __shared__ u32 lcnt[16];
    __shared__ u32 lbase[16];
    __shared__ ushort lrows[16 * 32];
    __shared__ u32 izn;
    __shared__ ushort izlist[512];

    if (blockIdx.x >= 512) {
        // ---- transpose path: 64x64 tiles ----
        float (*tile)[68] = reinterpret_cast<float(*)[68]>(smbig);
        int b = blockIdx.x - 512;
        const float* src; ushort* dst; int R, C, c0, r0, swz, ei;
        if (b < 512) {                     // W1: [512][256] -> [256][512] swz
            ei = b >> 5; int rem = b & 31;
            r0 = (rem >> 2) * 64; c0 = (rem & 3) * 64;
            R = DDIM; C = HDIM; swz = 1;
            src = W1; dst = W1T;
        } else {                           // W2: [256][64] -> [64][256]
            b -= 512;
            ei = b >> 2; int rem = b & 3;
            r0 = rem * 64; c0 = 0;
            R = HDIM; C = LDIM; swz = 0;
            src = W2; dst = W2T;
        }
        const int tr  = threadIdx.x >> 2;        // 0..63 source row
        const int tc4 = threadIdx.x & 3;         // 4 col-slots of 16

        const float* s = src + (size_t)ei * R * C + (size_t)(r0 + tr) * C + c0 + tc4 * 16;
        #pragma unroll
        for (int i = 0; i < 4; ++i) {
            float4 v = *reinterpret_cast<const float4*>(s + i * 4);
            *reinterpret_cast<float4*>(&tile[tr][tc4 * 16 + i * 4]) = v;
        }
        __syncthreads();

        ushort* d = dst + (size_t)ei * R * C;
        const int hh = c0 + tr;                  // output row (C-dim)
        #pragma unroll
        for (int i = 0; i < 4; ++i) {
            int rrb  = tc4 * 16 + i * 4;         // tile row = source-row offset
            int colb = r0 + rrb;                 // output col (R-dim)
            int col2 = colb;
            if (swz) {
                int g = (colb >> 3) & 7;
                col2 = (colb & ~63) | ((g ^ (hh & 7)) << 3) | (colb & 7);
            }
            ushort4 o;
            o.x = f2bf(tile[rrb + 0][tr]);
            o.y = f2bf(tile[rrb + 1][tr]);
            o.z = f2bf(tile[rrb + 2][tr]);
            o.w = f2bf(tile[rrb + 3][tr]);
            *reinterpret_cast<ushort4*>(&d[(size_t)hh * R + col2]) = o;
        }
        return;
    }

    // ---- gating path ----
    float* xs  = smbig;                  // [2][32*132]
    float* wtg = smbig + 2 * 32 * 132;   // [2][16*132]
    float* wtn = wtg   + 2 * 16 * 132;   // [2][16*132]

    const int t    = threadIdx.x;
    const int blk  = blockIdx.x;
    const int row0 = blk * 32;
    const int og   = t & 15, rg = t >> 4;
    const int sr   = t >> 3, sc = (t & 7) * 16;   // x-stage row/col
    const int sd   = t >> 1, se = (t & 1) * 8;    // w-stage d/e0

    if (t < 16) lcnt[t] = 0;
    if (t == 0) izn = 0;

    float4 xf0, xf1, xf2, xf3, wg0, wg1, wn0, wn1;
    const float* srcx0 = &x[(size_t)(row0 + sr) * DDIM + sc];

    // issue chunk-0 loads
    {
        const float4* p = reinterpret_cast<const float4*>(srcx0);
        xf0 = p[0]; xf1 = p[1]; xf2 = p[2]; xf3 = p[3];
        const float4* pg = reinterpret_cast<const float4*>(&wg[(size_t)sd * EEXP + se]);
        const float4* pn = reinterpret_cast<const float4*>(&wn[(size_t)sd * EEXP + se]);
        wg0 = pg[0]; wg1 = pg[1]; wn0 = pn[0]; wn1 = pn[1];
    }

    floatx4 accg4[2] = {}, accn4[2] = {};

    for (int ch = 0; ch < 4; ++ch) {
        const int k0  = ch * 128;
        const int buf = ch & 1;
        float* xsb = xs  + buf * (32 * 132);
        float* wgl = wtg + buf * (16 * 132);
        float* wnl = wtn + buf * (16 * 132);

        {   // LDS writes + xbf writeback (from regs loaded last iteration)
            float* dstx = &xsb[sr * 132 + sc];
            reinterpret_cast<float4*>(dstx)[0] = xf0;
            reinterpret_cast<float4*>(dstx)[1] = xf1;
            reinterpret_cast<float4*>(dstx)[2] = xf2;
            reinterpret_cast<float4*>(dstx)[3] = xf3;

            const int row = row0 + sr;
            const int sw  = sr & 7;
            #pragma unroll
            for (int i = 0; i < 2; ++i) {
                int cb = k0 + sc + i * 8;
                int kb = cb >> 6;
                int g  = (cb >> 3) & 7;
                int gp = g ^ sw;
                float4 a = (i == 0) ? xf0 : xf2;
                float4 b = (i == 0) ? xf1 : xf3;
                ushort8 t8;
                t8[0]=f2bf(a.x); t8[1]=f2bf(a.y); t8[2]=f2bf(a.z); t8[3]=f2bf(a.w);
                t8[4]=f2bf(b.x); t8[5]=f2bf(b.y); t8[6]=f2bf(b.z); t8[7]=f2bf(b.w);
                *reinterpret_cast<ushort8*>(&xbf[(size_t)row * DDIM + kb * 64 + gp * 8]) = t8;
            }

            wgl[(se+0)*132+sd]=wg0.x; wgl[(se+1)*132+sd]=wg0.y; wgl[(se+2)*132+sd]=wg0.z; wgl[(se+3)*132+sd]=wg0.w;
            wgl[(se+4)*132+sd]=wg1.x; wgl[(se+5)*132+sd]=wg1.y; wgl[(se+6)*132+sd]=wg1.z; wgl[(se+7)*132+sd]=wg1.w;
            wnl[(se+0)*132+sd]=wn0.x; wnl[(se+1)*132+sd]=wn0.y; wnl[(se+2)*132+sd]=wn0.z; wnl[(se+3)*132+sd]=wn0.w;
            wnl[(se+4)*132+sd]=wn1.x; wnl[(se+5)*132+sd]=wn1.y; wnl[(se+6)*132+sd]=wn1.z; wnl[(se+7)*132+sd]=wn1.w;
        }

        if (ch < 3) {   // issue next chunk's loads; land during barrier+compute
            const int k1 = k0 + 128;
            const float4* p = reinterpret_cast<const float4*>(srcx0 + k1);
            xf0 = p[0]; xf1 = p[1]; xf2 = p[2]; xf3 = p[3];
            const float4* pg = reinterpret_cast<const float4*>(&wg[(size_t)(k1 + sd) * EEXP + se]);
            const float4* pn = reinterpret_cast<const float4*>(&wn[(size_t)(k1 + sd) * EEXP + se]);
            wg0 = pg[0]; wg1 = pg[1]; wn0 = pn[0]; wn1 = pn[1];
        }

        __syncthreads();   // single barrier/chunk (writes go to buf^1 next)

        #pragma unroll 8
        for (int d4 = 0; d4 < 32; ++d4) {
            floatx4 wgv = *reinterpret_cast<const floatx4*>(&wgl[og * 132 + d4 * 4]);
            floatx4 wnv = *reinterpret_cast<const floatx4*>(&wnl[og * 132 + d4 * 4]);
            #pragma unroll
            for (int rr = 0; rr < 2; ++rr) {
                floatx4 xv = *reinterpret_cast<const floatx4*>(&xsb[(rg * 2 + rr) * 132 + d4 * 4]);
                accg4[rr] += xv * wgv;
                accn4[rr] += xv * wnv;
            }
        }
    }

    #pragma unroll
    for (int rr = 0; rr < 2; ++rr) {
        const int row = row0 + rg * 2 + rr;
        float accg = accg4[rr][0] + accg4[rr][1] + accg4[rr][2] + accg4[rr][3];
        float accn = accn4[rr][0] + accn4[rr][1] + accn4[rr][2] + accn4[rr][3];

        // keep libcall-precision softplus: gate threshold flips are the risk
        float sp = fmaxf(accn, 0.f) + log1pf(expf(-fabsf(accn)));
        float stddev = sp + 0.01f;
        float nz = noise[(size_t)row * EEXP + og];
        float z = accg + nz * stddev;

        float m = z;
        #pragma unroll
        for (int mask = 8; mask >= 1; mask >>= 1)
            m = fmaxf(m, __shfl_xor(m, mask, 16));
        float ez = expf(z - m);
        float s = ez;
        #pragma unroll
        for (int mask = 8; mask >= 1; mask >>= 1)
            s += __shfl_xor(s, mask, 16);
        float logit = ez / s;

        float lsum = logit;
        #pragma unroll
        for (int mask = 8; mask >= 1; mask >>= 1)
            lsum += __shfl_xor(lsum, mask, 16);
        float mean = lsum * (1.0f / 16.0f) - 1e-8f;

        float gate = (logit >= mean) ? logit : 0.0f;
        float denom = gate;
        #pragma unroll
        for (int mask = 8; mask >= 1; mask >>= 1)
            denom += __shfl_xor(denom, mask, 16);

        gates[(size_t)row * EEXP + og] = gate / denom;

        if (gate > 0.0f) {
            u32 p = atomicAdd(&lcnt[og], 1u);
            lrows[og * 32 + p] = (ushort)(rg * 2 + rr);
        } else {
            u32 p = atomicAdd(&izn, 1u);
            izlist[p] = (ushort)((rg * 2 + rr) * 16 + og);
        }
    }

    __syncthreads();
    if (t < 16) lbase[t] = atomicAdd(&cnt[t], lcnt[t]);

    // Coalesced zero-fill: 16 consecutive threads per inactive slot write one
    // contiguous 256-B segment (16 x float4).
    {
        const u32 ni = izn;
        const int grp = t >> 4, l16 = t & 15;
        float4* o4 = reinterpret_cast<float4*>(out);
        const float4 zf = {0.f, 0.f, 0.f, 0.f};
        for (u32 i = grp; i < ni; i += 16) {
            int slot = izlist[i];
            int rl = slot >> 4, e = slot & 15;
            o4[(size_t)(row0 + rl) * 256 + e * 16 + l16] = zf;
        }
    }

    __syncthreads();
    for (int i = t; i < 16 * 32; i += 256) {
        int e = i >> 5, j = i & 31;
        if ((u32)j < lcnt[e])
            rowlist[(size_t)e * BROWS + lbase[e] + j] = row0 + lrows[e * 32 + j];
    }
}

// ---------------------------------------------------------------------------
// Sparse expert MLP, BM=64, 40 KB LDS -> 4 blocks/CU. Byte-identical to the
// best-measured (R7) structure: synchronized K-phases across blocks give
// cross-block W1T fetch-sharing in L2 (R8's desync raised FETCH 38.8->41.6 MB
// and cost +5.5 us -> reverted). e = bx&15 pins each expert's W1T to one
// XCD-pair's L2.
// ---------------------------------------------------------------------------
__global__ __launch_bounds__(256, 4) void expert_kernel(
    const ushort* __restrict__ xbf,    // [B][D] bf16, swizzled
    const float*  __restrict__ gates,  // [B][E]
    const ushort* __restrict__ W1T,    // [E][H][D] bf16, swizzled
    const float*  __restrict__ b1,     // [E][H]
    const ushort* __restrict__ W2T,    // [E][L][H] bf16, linear
    const float*  __restrict__ b2,     // [E][L]
    const u32*    __restrict__ cnt,    // [E]
    const u32*    __restrict__ rowlist,// [E][B]
    float* __restrict__ out)           // [B][E][L]
{
    __shared__ __align__(16) ushort lds[20480];  // A [0,8K)B, B [8K,40K)B; h [0,32K)B

    const int bx = blockIdx.x;
    const int e  = bx & 15;
    const int t  = bx >> 4;

    const int count = (int)cnt[e];
    if (t * BM >= count) return;
    const int nrt = min(BM, count - t * BM);
    const u32* rl = rowlist + (size_t)e * BROWS + t * BM;

    const int tid  = threadIdx.x;
    const int lane = tid & 63;
    const int wave = tid >> 6;

    const int lr = lane & 15;
    const int q  = lane >> 4;
    const int kq = q * 8;
    const int rq = q * 4;
    const int la = lane >> 3, lb = lane & 7;  // staging lane split

    const char* xg = (const char*)xbf;
    const char* w1 = (const char*)W1T + (size_t)e * HDIM * 1024;

    // Per-lane gathered A-row bases + swizzle re-key terms
    size_t abase[2]; int sxr[2];
    #pragma unroll
    for (int p = 0; p < 2; ++p) {
        int r  = wave * 16 + p * 8 + la;
        int rc = min(r, nrt - 1);
        u32 ri = rl[rc];
        abase[p] = (size_t)ri * 1024;
        sxr[p]   = (la ^ (int)(ri & 7)) << 4;
    }

    floatx4 acc[4][4] = {};

    for (int kb = 0; kb < 8; ++kb) {
        const int koff = kb * 128;   // byte offset within 1024-B row
        #pragma unroll
        for (int p = 0; p < 2; ++p) {   // A tile: 8 KB (gathered rows)
            int c = wave * 2 + p;
            gl_lds16(xg + abase[p] + koff + ((lb << 4) ^ sxr[p]), &lds[c * 512]);
        }
        #pragma unroll
        for (int p = 0; p < 8; ++p) {   // B tile: 32 KB (sequential W1T rows)
            int c = wave * 8 + p;
            gl_lds16(w1 + (size_t)(c * 8 + la) * 1024 + koff + (lb << 4),
                     &lds[4096 + c * 512]);
        }
        __syncthreads();

        #pragma unroll
        for (int s = 0; s < 2; ++s) {
            const int g = s * 4 + q;
            bf16x8 af[4], bfr[4];
            #pragma unroll
            for (int i = 0; i < 4; ++i) {
                int r = i * 16 + lr;
                af[i] = *reinterpret_cast<const bf16x8*>(&lds[r * 64 + ((g ^ (r & 7)) << 3)]);
            }
            #pragma unroll
            for (int j = 0; j < 4; ++j) {
                int r = wave * 64 + j * 16 + lr;
                bfr[j] = *reinterpret_cast<const bf16x8*>(&lds[4096 + r * 64 + ((g ^ (r & 7)) << 3)]);
            }
            #pragma unroll
            for (int i = 0; i < 4; ++i)
                #pragma unroll
                for (int j = 0; j < 4; ++j)
                    acc[i][j] = __builtin_amdgcn_mfma_f32_16x16x32_bf16(
                        af[i], bfr[j], acc[i][j], 0, 0, 0);
        }
        __syncthreads();
    }

    // h = fast_tanh(acc + b1) -> bf16, swizzled [64][256] at lds[0..32K)
    float b1v[4];
    #pragma unroll
    for (int j = 0; j < 4; ++j)
        b1v[j] = b1[e * HDIM + wave * 64 + j * 16 + lr];

    #pragma unroll
    for (int i = 0; i < 4; ++i)
        #pragma unroll
        for (int j = 0; j < 4; ++j) {
            int c = wave * 64 + j * 16 + lr;
            int gg = c >> 3;
            #pragma unroll
            for (int rr = 0; rr < 4; ++rr) {
                int r = i * 16 + rq + rr;
                float v = fast_tanh(acc[i][j][rr] + b1v[j]);
                lds[r * 256 + (((gg & 24) | ((gg & 7) ^ (r & 7))) << 3) + (c & 7)] = f2bf(v);
            }
        }
    __syncthreads();

    // Phase B: y[64][64]; wave owns rows [wave*16,+16); W2 frags from global
    const ushort* w2 = W2T + (size_t)e * LDIM * HDIM;
    floatx4 acc2[4] = {};
    #pragma unroll
    for (int s = 0; s < 8; ++s) {
        int r = wave * 16 + lr;
        int g = s * 4 + q;
        bf16x8 af = *reinterpret_cast<const bf16x8*>(
            &lds[r * 256 + (((g & 24) | ((g & 7) ^ (r & 7))) << 3)]);
        #pragma unroll
        for (int j = 0; j < 4; ++j) {
            bf16x8 bfr = *reinterpret_cast<const bf16x8*>(
                &w2[(size_t)(j * 16 + lr) * HDIM + s * 32 + kq]);
            acc2[j] = __builtin_amdgcn_mfma_f32_16x16x32_bf16(af, bfr, acc2[j], 0, 0, 0);
        }
    }

    float b2v[4];
    #pragma unroll
    for (int j = 0; j < 4; ++j)
        b2v[j] = b2[e * LDIM + j * 16 + lr];

    #pragma unroll
    for (int rr = 0; rr < 4; ++rr) {
        int r  = wave * 16 + rq + rr;
        int rc = min(r, nrt - 1);
        u32 ri = rl[rc];
        float gsc = gates[(size_t)ri * EEXP + e];
        if (r < nrt) {
            #pragma unroll
            for (int j = 0; j < 4; ++j)
                out[(size_t)ri * (EEXP * LDIM) + e * LDIM + j * 16 + lr] =
                    (acc2[j][rr] + b2v[j]) * gsc;
        }
    }
}

// ---------------------------------------------------------------------------
extern "C" void kernel_launch(void* const* d_in, const int* in_sizes, int n_in,
                              void* d_out, int out_size, void* d_ws, size_t ws_size,
                              hipStream_t stream) {
    (void)in_sizes; (void)n_in; (void)out_size; (void)ws_size;
    const float* x     = (const float*)d_in[0];
    const float* noise = (const float*)d_in[1];
    const float* wg    = (const float*)d_in[2];
    const float* wn    = (const float*)d_in[3];
    const float* W1    = (const float*)d_in[4];
    const float* b1    = (const float*)d_in[5];
    const float* W2    = (const float*)d_in[6];
    const float* b2    = (const float*)d_in[7];
    float* out = (float*)d_out;

    char* ws = (char*)d_ws;
    float*  gates   = (float*)ws;                          // 1 MiB
    ushort* W1T     = (ushort*)(ws + (1 << 20));           // 4 MiB
    ushort* W2T     = (ushort*)(ws + (5 << 20));           // 0.5 MiB
    ushort* xbf     = (ushort*)(ws + (6 << 20));           // 16 MiB
    u32*    cnt     = (u32*)(ws + (22 << 20));             // 64 B
    u32*    rowlist = (u32*)(ws + (24 << 20));             // 1 MiB

    hipMemsetAsync(cnt, 0, EEXP * sizeof(u32), stream);
    gate_aux_kernel<<<512 + 576, 256, 0, stream>>>(
        x, noise, wg, wn, W1, W2, gates, xbf, W1T, W2T, cnt, rowlist, out);
    expert_kernel<<<(BROWS / BM) * EEXP, 256, 0, stream>>>(
        xbf, gates, W1T, b1, W2T, b2, cnt, rowlist, out);
}